// Round 11
// baseline (1099.478 us; speedup 1.0000x reference)
//
#include <hip/hip_runtime.h>
#include <hip/hip_bf16.h>

#define NN 1000000
#define NG 15625   // NN / 64 nodes per group

typedef _Float16 f16x8 __attribute__((ext_vector_type(8)));
typedef _Float16 h2    __attribute__((ext_vector_type(2)));
typedef float f32x4    __attribute__((ext_vector_type(4)));
typedef unsigned short u16x8 __attribute__((ext_vector_type(8)));
typedef unsigned short u16x4 __attribute__((ext_vector_type(4)));

__device__ __forceinline__ unsigned short f2h(float v){
  _Float16 h = (_Float16)v; unsigned short s;
  __builtin_memcpy(&s, &h, 2); return s;
}

// ---------------- Layer 2: h1(fp16)[1M,128] -> out(f32)[1M,128] ----------------
// 256 thr = 4 waves; group = 64 nodes; wave w owns cols [w*32, w*32+32).
// (256,3): VGPR cap 170 -> full stash+Bf+acc (~165) lives, 3 indep blocks/CU.
// selfS: double-buffered global_load_lds DMA (linear dest, pre-swizzled source).
// aggS: register-gathered neighbors, packed-fp16 masked mean.
__global__ __launch_bounds__(256, 3) void sage2_mfma(
    const unsigned short* __restrict__ h1, const float* __restrict__ W2,
    const int* __restrict__ nidx, const int* __restrict__ nmask,
    float* __restrict__ out)
{
  __shared__ unsigned short selfS[2][64 * 128];  // 2 x 16 KB (DMA target)
  __shared__ unsigned short aggS[64 * 128];      // 16 KB
  __shared__ float red[64][4];
  const int t   = threadIdx.x;
  const int l   = t & 63;
  const int w   = t >> 6;       // 0..3
  const int cfr = l & 15;
  const int kg  = l >> 4;

  // B frags (fp16): col = w*32 + nf*16 + cfr; Bf[ks][nf], ks<4 self-K, ks>=4 agg-K
  f16x8 Bf[8][2];
  #pragma unroll
  for (int ks = 0; ks < 8; ++ks) {
    #pragma unroll
    for (int nf = 0; nf < 2; ++nf) {
      const int col = w*32 + nf*16 + cfr;
      const float* p = W2 + col*256 + ks*32 + kg*8;
      f32x4 a = *reinterpret_cast<const f32x4*>(p);
      f32x4 b = *reinterpret_cast<const f32x4*>(p + 4);
      f16x8 v;
      v[0]=(_Float16)a[0]; v[1]=(_Float16)a[1]; v[2]=(_Float16)a[2]; v[3]=(_Float16)a[3];
      v[4]=(_Float16)b[0]; v[5]=(_Float16)b[1]; v[6]=(_Float16)b[2]; v[7]=(_Float16)b[3];
      Bf[ks][nf] = v;
    }
  }

  const u16x8* hp = reinterpret_cast<const u16x8*>(h1);
  char* aggB = reinterpret_cast<char*>(aggS);

  u16x8 s0[4], s1[4], s2[4];                 // neighbor stash: 48 VGPRs
  _Float16 m0h[4], m1h[4], m2h[4], ivh[4];

  // idx loads + dependent gathers, issued together after barrier1 (latency
  // covered by the MFMA+epilogue phase; idx kept 1-deep to stay under VGPR cap).
  auto GATHER = [&](int g){
    const long gb = (long)g * 64;
    #pragma unroll
    for (int i = 0; i < 4; ++i) {
      int it = t + i*256;
      int n = it >> 4, q = it & 15;
      long node = gb + n;
      int j0 = nidx[node*3+0], j1 = nidx[node*3+1], j2 = nidx[node*3+2];
      int b0 = nmask[node*3+0], b1 = nmask[node*3+1], b2 = nmask[node*3+2];
      m0h[i]=(_Float16)(float)b0; m1h[i]=(_Float16)(float)b1; m2h[i]=(_Float16)(float)b2;
      int c = b0+b1+b2; ivh[i] = (_Float16)(1.0f/(float)(c<1?1:c));
      u16x8 z = {};
      s0[i] = b0 ? hp[(long)j0*16 + q] : z;
      s1[i] = b1 ? hp[(long)j1*16 + q] : z;
      s2[i] = b2 ? hp[(long)j2*16 + q] : z;
    }
  };
  // Self rows via DMA: item it -> (node it>>4, chunk it&15). LDS dest LINEAR at
  // it*16 B (wave-uniform base + lane*16); source chunk pre-swizzled q^(n&7).
  auto SELF_DMA = [&](int g, int pp){
    #pragma unroll
    for (int i = 0; i < 4; ++i) {
      int it = t + i*256;
      int nn = it >> 4, qq0 = it & 15;
      long node = (long)g * 64 + nn;
      int qq = qq0 ^ (nn & 7);
      const unsigned short* gp = h1 + node*128 + qq*8;
      unsigned short* lp = &selfS[pp][it*8];
      __builtin_amdgcn_global_load_lds(
          (const __attribute__((address_space(1))) unsigned short*)gp,
          (__attribute__((address_space(3))) unsigned short*)lp, 16, 0, 0);
    }
  };
  auto UNPACK_AGG = [&](){
    #pragma unroll
    for (int i = 0; i < 4; ++i) {
      int it = t + i*256;
      int n = it >> 4, q = it & 15;
      int sw = (n & 7) << 4;
      h2 A[4], B4[4], C4[4], R[4];
      __builtin_memcpy(A,  &s0[i], 16);
      __builtin_memcpy(B4, &s1[i], 16);
      __builtin_memcpy(C4, &s2[i], 16);
      h2 M0 = {m0h[i], m0h[i]}, M1 = {m1h[i], m1h[i]},
         M2 = {m2h[i], m2h[i]}, IV = {ivh[i], ivh[i]};
      #pragma unroll
      for (int j = 0; j < 4; ++j)
        R[j] = (A[j]*M0 + B4[j]*M1 + C4[j]*M2) * IV;
      u16x8 r; __builtin_memcpy(&r, R, 16);
      *reinterpret_cast<u16x8*>(aggB + n*256 + ((q*16) ^ sw)) = r;
    }
  };

  const int g0 = blockIdx.x;
  GATHER(g0); SELF_DMA(g0, 0);

  int p = 0;
  for (int g = g0; g < NG; g += gridDim.x) {
    const long gb = (long)g * 64;
    UNPACK_AGG();                      // consumes stash(g)
    __syncthreads();                   // selfS[p] DMA drained + aggS visible

    int g1 = g + gridDim.x;
    if (g1 < NG) { SELF_DMA(g1, p ^ 1); GATHER(g1); }   // in flight across MFMA

    f32x4 acc[4][2];
    #pragma unroll
    for (int r = 0; r < 4; ++r) {
      acc[r][0] = (f32x4){0.f,0.f,0.f,0.f};
      acc[r][1] = (f32x4){0.f,0.f,0.f,0.f};
    }
    const int swz = (cfr & 7) << 4;
    char* selfB = reinterpret_cast<char*>(selfS) + p*(64*256);
    #pragma unroll
    for (int r = 0; r < 4; ++r) {
      const int rb = (r*16 + cfr) * 256;
      #pragma unroll
      for (int ks = 0; ks < 4; ++ks) {
        f16x8 af = *reinterpret_cast<const f16x8*>(selfB + rb + ((ks*64 + kg*16) ^ swz));
        acc[r][0] = __builtin_amdgcn_mfma_f32_16x16x32_f16(af, Bf[ks][0], acc[r][0], 0,0,0);
        acc[r][1] = __builtin_amdgcn_mfma_f32_16x16x32_f16(af, Bf[ks][1], acc[r][1], 0,0,0);
      }
      #pragma unroll
      for (int ks = 0; ks < 4; ++ks) {
        f16x8 af = *reinterpret_cast<const f16x8*>(aggB + rb + ((ks*64 + kg*16) ^ swz));
        acc[r][0] = __builtin_amdgcn_mfma_f32_16x16x32_f16(af, Bf[ks+4][0], acc[r][0], 0,0,0);
        acc[r][1] = __builtin_amdgcn_mfma_f32_16x16x32_f16(af, Bf[ks+4][1], acc[r][1], 0,0,0);
      }
    }

    float ssv[4][4];
    #pragma unroll
    for (int r = 0; r < 4; ++r) {
      #pragma unroll
      for (int e = 0; e < 4; ++e) {
        float v0 = fmaxf(acc[r][0][e], 0.f); acc[r][0][e] = v0;
        float v1 = fmaxf(acc[r][1][e], 0.f); acc[r][1][e] = v1;
        float s = v0*v0 + v1*v1;
        s += __shfl_xor(s, 1); s += __shfl_xor(s, 2);
        s += __shfl_xor(s, 4); s += __shfl_xor(s, 8);
        ssv[r][e] = s;
      }
      if (cfr < 4) {
        float v = cfr==0 ? ssv[r][0] : cfr==1 ? ssv[r][1] : cfr==2 ? ssv[r][2] : ssv[r][3];
        red[r*16 + kg*4 + cfr][w] = v;
      }
    }
    __syncthreads();

    #pragma unroll
    for (int r = 0; r < 4; ++r) {
      #pragma unroll
      for (int e = 0; e < 4; ++e) {
        int row = r*16 + kg*4 + e;
        float tot = red[row][0] + red[row][1] + red[row][2] + red[row][3];
        float inv = 1.0f / fmaxf(sqrtf(tot), 1e-12f);
        out[(gb + row)*128 + w*32 + cfr]      = acc[r][0][e] * inv;
        out[(gb + row)*128 + w*32 + 16 + cfr] = acc[r][1][e] * inv;
      }
    }
    p ^= 1;
  }
}

// ---------------- Layer 1: x(f32)[1M,57] -> h1(fp16)[1M,128] ----------------
// Proven structure (~280us): 256 thr, 64-node groups, scalar jv-guarded gathers
// (x rows are 228B — unaligned; vectorization regressed in R9), grid 2048, (256,2).
// LDS K-layout: [0,57)=self, [57,64)=0, [64,121)=agg, [121,128)=0.
__global__ __launch_bounds__(256, 2) void sage1_mfma(
    const float* __restrict__ x, const float* __restrict__ W1,
    const int* __restrict__ nidx, const int* __restrict__ nmask,
    unsigned short* __restrict__ h1)
{
  __shared__ unsigned short comb[64 * 128];
  __shared__ float red[64][4];
  const int t   = threadIdx.x;
  const int l   = t & 63;
  const int w   = t >> 6;
  const int cfr = l & 15;
  const int kg  = l >> 4;

  // B fragments (fp16), K remapped: lds_k<57 -> k=lds_k; 64<=lds_k<121 -> k=lds_k-7.
  f16x8 Bf[4][2];
  #pragma unroll
  for (int ks = 0; ks < 4; ++ks) {
    #pragma unroll
    for (int nf = 0; nf < 2; ++nf) {
      const int col = w*32 + nf*16 + cfr;
      const int k0  = ks*32 + kg*8;
      f16x8 v;
      #pragma unroll
      for (int j = 0; j < 8; ++j) {
        int lk = k0 + j;
        int wk = lk < 64 ? lk : lk - 7;
        bool valid = (lk < 57) || (lk >= 64 && lk < 121);
        v[j] = valid ? (_Float16)W1[col*114 + wk] : (_Float16)0.0f;
      }
      Bf[ks][nf] = v;
    }
  }

  char* cb = reinterpret_cast<char*>(comb);

  f32x4 sf[4], n0[4], n1[4], n2[4];
  float m0[4], m1[4], m2[4], iv[4];

  auto ISSUE = [&](int g){
    const long gb = (long)g * 64;
    #pragma unroll
    for (int i = 0; i < 4; ++i) {
      int it = t + i*256;
      int n = it >> 4, q = it & 15;
      long node = gb + n;
      int j0 = nidx[node*3+0], j1 = nidx[node*3+1], j2 = nidx[node*3+2];
      int b0 = nmask[node*3+0], b1 = nmask[node*3+1], b2 = nmask[node*3+2];
      m0[i]=(float)b0; m1[i]=(float)b1; m2[i]=(float)b2;
      int c = b0+b1+b2; iv[i] = 1.0f/(float)(c<1?1:c);
      #pragma unroll
      for (int jj = 0; jj < 4; ++jj) {
        int j = q*4 + jj;
        bool jv = j < 57;
        sf[i][jj] = jv         ? x[node*57 + j]     : 0.f;
        n0[i][jj] = (b0 && jv) ? x[(long)j0*57 + j] : 0.f;
        n1[i][jj] = (b1 && jv) ? x[(long)j1*57 + j] : 0.f;
        n2[i][jj] = (b2 && jv) ? x[(long)j2*57 + j] : 0.f;
      }
    }
  };

  if (blockIdx.x < NG) ISSUE(blockIdx.x);

  for (int g = blockIdx.x; g < NG; g += gridDim.x) {
    const long gb = (long)g * 64;
    #pragma unroll
    for (int i = 0; i < 4; ++i) {
      int it = t + i*256;
      int n = it >> 4, q = it & 15;
      int sw = (n & 7) << 4;
      u16x4 vs, va;
      #pragma unroll
      for (int jj = 0; jj < 4; ++jj) {
        vs[jj] = f2h(sf[i][jj]);
        va[jj] = f2h((m0[i]*n0[i][jj] + m1[i]*n1[i][jj] + m2[i]*n2[i][jj]) * iv[i]);
      }
      *reinterpret_cast<u16x4*>(cb + n*256 + ((q*8) ^ sw))       = vs;
      *reinterpret_cast<u16x4*>(cb + n*256 + ((128 + q*8) ^ sw)) = va;
    }
    __syncthreads();

    int gn = g + gridDim.x;
    if (gn < NG) ISSUE(gn);

    f32x4 acc[4][2];
    #pragma unroll
    for (int r = 0; r < 4; ++r) {
      acc[r][0] = (f32x4){0.f,0.f,0.f,0.f};
      acc[r][1] = (f32x4){0.f,0.f,0.f,0.f};
    }
    const int swz = (cfr & 7) << 4;
    #pragma unroll
    for (int r = 0; r < 4; ++r) {
      const int rb = (r*16 + cfr) * 256;
      #pragma unroll
      for (int ks = 0; ks < 4; ++ks) {
        f16x8 af = *reinterpret_cast<const f16x8*>(cb + rb + ((ks*64 + kg*16) ^ swz));
        acc[r][0] = __builtin_amdgcn_mfma_f32_16x16x32_f16(af, Bf[ks][0], acc[r][0], 0,0,0);
        acc[r][1] = __builtin_amdgcn_mfma_f32_16x16x32_f16(af, Bf[ks][1], acc[r][1], 0,0,0);
      }
    }

    float ssv[4][4];
    #pragma unroll
    for (int r = 0; r < 4; ++r) {
      #pragma unroll
      for (int e = 0; e < 4; ++e) {
        float v0 = fmaxf(acc[r][0][e], 0.f); acc[r][0][e] = v0;
        float v1 = fmaxf(acc[r][1][e], 0.f); acc[r][1][e] = v1;
        float s = v0*v0 + v1*v1;
        s += __shfl_xor(s, 1); s += __shfl_xor(s, 2);
        s += __shfl_xor(s, 4); s += __shfl_xor(s, 8);
        ssv[r][e] = s;
      }
      if (cfr < 4) {
        float v = cfr==0 ? ssv[r][0] : cfr==1 ? ssv[r][1] : cfr==2 ? ssv[r][2] : ssv[r][3];
        red[r*16 + kg*4 + cfr][w] = v;
      }
    }
    __syncthreads();

    #pragma unroll
    for (int r = 0; r < 4; ++r) {
      #pragma unroll
      for (int e = 0; e < 4; ++e) {
        int row = r*16 + kg*4 + e;
        float tot = red[row][0] + red[row][1] + red[row][2] + red[row][3];
        float inv = 1.0f / fmaxf(sqrtf(tot), 1e-12f);
        long node = gb + row;
        h1[node*128 + w*32 + cfr]      = f2h(acc[r][0][e] * inv);
        h1[node*128 + w*32 + 16 + cfr] = f2h(acc[r][1][e] * inv);
      }
    }
  }
}

extern "C" void kernel_launch(void* const* d_in, const int* in_sizes, int n_in,
                              void* d_out, int out_size, void* d_ws, size_t ws_size,
                              hipStream_t stream) {
  const float* x   = (const float*)d_in[0];
  const float* W1  = (const float*)d_in[1];
  const float* W2  = (const float*)d_in[2];
  const int* idx1  = (const int*)d_in[3];
  const int* msk1  = (const int*)d_in[4];
  const int* idx2  = (const int*)d_in[5];
  const int* msk2  = (const int*)d_in[6];
  float* out = (float*)d_out;
  unsigned short* h1 = (unsigned short*)d_ws;   // fp16 [1M,128] = 256 MB

  sage1_mfma<<<2048, 256, 0, stream>>>(x, W1, idx1, msk1, h1);
  sage2_mfma<<<768,  256, 0, stream>>>(h1, W2, idx2, msk2, out);
}